// Round 10
// baseline (109.530 us; speedup 1.0000x reference)
//
#include <hip/hip_runtime.h>

// Bahdanau attention. query [8][400][256], y [8][400][256], Wq_w [128][256],
// Wq_b [128], Wy_w [128][256], Wy_b [128], v_w [1][128], v_b (dropped:
// softmax shift-invariant), n_wins_y [8] i32. out [8][400][256] f32.
//
// score = sum_a v_a*tanh(qp+yp) ~ const - sum_a 2 v_a/(Eq_a*Ey_a + 1),
// Eq = e^{2 qp}, Ey = e^{2 yp} precomputed.
//
// R10 lesson stack:
//  - R4: no runtime-indexed register arrays (scratch spill).
//  - R7: no lane-scattered global reads (W transposed in K0).
//  - R10: LDS instruction pipe (~12cyc/ds_read_b128/CU) was the global
//    bottleneck (R9 score: 3 LDS reads/iter ~ 33us). ALL wave-uniform
//    broadcast data now reads from GLOBAL (scalar s_load / L1 broadcast
//    pipe); LDS kept ONLY for per-lane-unique data (Ey^T tile, p rows).

#define LOG2E 1.4426950408889634f
#define TANH_SCALE 2.8853900817779268f  // 2*log2(e)

constexpr int TQn = 400, TYn = 400, AD = 128, DD = 256;
constexpr int QT = 8;               // q per fused block
constexpr int QBLOCKS = TQn / QT;   // 50
constexpr int SSTR = 65;            // Ey^T tile stride (float4)
constexpr int PROW = 404;           // s_p row stride (floats); rows 16B-aligned

// ---------------- K0: WT4[k4][a] = W[a][4k4..4k4+3] ------------------------
__global__ __launch_bounds__(128) void transpose_kernel(
    const float* __restrict__ Wq, const float* __restrict__ Wy,
    float4* __restrict__ WTq, float4* __restrict__ WTy)
{
    const int k4 = blockIdx.x & 63;
    const bool isq = blockIdx.x < 64;
    const float4* src = reinterpret_cast<const float4*>(isq ? Wq : Wy);
    float4* dst = isq ? WTq : WTy;
    const int a = threadIdx.x;                 // 0..127
    dst[k4 * 128 + a] = src[a * 64 + k4];
}

// ---------------- K1: Eq = exp(2(Wq q + b)); Ey likewise -------------------
// No LDS. Input rows read at wave-uniform addresses (scalar path); W lane-
// coalesced. 400 blocks x 256 thr; 16 rows/block (a = tid&127, rh = tid>>7).
__global__ __launch_bounds__(256) void proj_kernel(
    const float* __restrict__ qin, const float* __restrict__ yin,
    const float4* __restrict__ WTq, const float* __restrict__ bq,
    const float4* __restrict__ WTy, const float* __restrict__ by,
    float* __restrict__ Eq, float* __restrict__ Ey)
{
    const int blk = blockIdx.x;               // [0,200) q, [200,400) y
    const bool is_q = blk < 200;
    const int row0 = (is_q ? blk : blk - 200) * 16;
    const int a  = threadIdx.x & 127;
    const int rh = threadIdx.x >> 7;          // 0/1: rows rh*8 .. rh*8+7
    const float4* in4 = reinterpret_cast<const float4*>(
        (is_q ? qin : yin) + (size_t)(row0 + rh * 8) * DD);  // wave-uniform base
    const float4* wt  = is_q ? WTq : WTy;     // [64 k4][128 a]
    const float* bias = is_q ? bq : by;
    float* outp = (is_q ? Eq : Ey) + (size_t)(row0 + rh * 8) * AD;

    float acc[8] = {0.f,0.f,0.f,0.f,0.f,0.f,0.f,0.f};
    for (int c = 0; c < 8; ++c) {             // k4 chunk: c*8 .. c*8+7
        float4 wreg[8];
        #pragma unroll
        for (int j = 0; j < 8; ++j)
            wreg[j] = wt[(c * 8 + j) * 128 + a];   // lane-coalesced 16B
        #pragma unroll
        for (int r = 0; r < 8; ++r) {
            #pragma unroll
            for (int j = 0; j < 8; ++j) {
                float4 v = in4[r * 64 + c * 8 + j]; // wave-uniform -> s_load
                acc[r] = fmaf(wreg[j].x, v.x, acc[r]);
                acc[r] = fmaf(wreg[j].y, v.y, acc[r]);
                acc[r] = fmaf(wreg[j].z, v.z, acc[r]);
                acc[r] = fmaf(wreg[j].w, v.w, acc[r]);
            }
        }
    }
    const float bb = bias[a];
    #pragma unroll
    for (int r = 0; r < 8; ++r)
        outp[(size_t)r * AD + a] =
            __builtin_amdgcn_exp2f((acc[r] + bb) * TANH_SCALE);
}

// ---------------- K2: fused scores -> softmax -> att@y ---------------------
__global__ __launch_bounds__(256) void fused_kernel(
    const float* __restrict__ y,    // [B][TY][DD]
    const float* __restrict__ Eq,   // [B*TQ][AD]
    const float* __restrict__ Ey,   // [B*TY][AD]
    const float* __restrict__ vw,   // [AD]
    const int*  __restrict__ nwins, // [B]
    float* __restrict__ out)        // [B][TQ][DD]
{
    __shared__ float4 s_ey[32 * SSTR];               // 33.3 KB, Ey^T [a4][t]
    __shared__ __align__(16) float s_p[QT][PROW];    // 12.9 KB

    const int b  = blockIdx.x / QBLOCKS;
    const int q0 = (blockIdx.x % QBLOCKS) * QT;
    const int tid = threadIdx.x;          // 0..255
    const int wave = tid >> 6;            // 0..3; handles q {wave, wave+4}
    const int lane = tid & 63;            // t within score tile
    const int n = nwins[b];
    const float NEG_INF = -__builtin_inff();

    const float4* eyb = reinterpret_cast<const float4*>(Ey);
    const float4* yb4 = reinterpret_cast<const float4*>(y) + (size_t)(b * TYn) * 64;
    const float4* vw4 = reinterpret_cast<const float4*>(vw);
    const float4* eqlo = reinterpret_cast<const float4*>(Eq)
                       + (size_t)(b * TQn + q0 + wave) * 32;   // wave-uniform
    const float4* eqhi = eqlo + 4 * 32;                        // q + 4

    const int scol = tid & 31;            // a4 staging col
    const int srow = tid >> 5;            // 0..7 staging row base

    float sc_lo[7], sc_hi[7];
    #pragma unroll
    for (int j = 0; j < 7; ++j) { sc_lo[j] = NEG_INF; sc_hi[j] = NEG_INF; }
    const int ntile = (n + 63) >> 6;      // 4..7, block-uniform

    // ---- score: constant-trip guarded loop (R4), 1 LDS read per iter ----
    #pragma unroll
    for (int i = 0; i < 7; ++i) {
        if (i < ntile) {
            const int t0 = i * 64;
            __syncthreads();              // prior tile's reads done
            #pragma unroll
            for (int k = 0; k < 8; ++k) {
                const int r = min(t0 + srow + 8 * k, TYn - 1);
                s_ey[scol * SSTR + srow + 8 * k] =
                    eyb[(size_t)(b * TYn + r) * 32 + scol];  // coalesced 512B
            }
            __syncthreads();
            float al0 = 0.f, al1 = 0.f, al2 = 0.f, al3 = 0.f;
            float ah0 = 0.f, ah1 = 0.f, ah2 = 0.f, ah3 = 0.f;
            #pragma unroll 8
            for (int a4 = 0; a4 < 32; ++a4) {
                const float4 yv = s_ey[a4 * SSTR + lane];  // per-lane LDS (only)
                const float4 vv = vw4[a4];                 // uniform global
                {
                    const float4 qv = eqlo[a4];            // uniform global
                    float a0 = fmaf(qv.x, yv.x, 1.f);
                    float a1 = fmaf(qv.y, yv.y, 1.f);
                    float a2 = fmaf(qv.z, yv.z, 1.f);
                    float a3 = fmaf(qv.w, yv.w, 1.f);
                    float p01 = a0 * a1, p23 = a2 * a3;
                    float R = __builtin_amdgcn_rcpf(p01 * p23);
                    float t1 = p23 * R, t2 = p01 * R;
                    float u = t1 + t1, w2 = t2 + t2;       // 2/p01, 2/p23
                    al0 = fmaf(vv.x, -(a1 * u),  al0);     // -2 v / a0
                    al1 = fmaf(vv.y, -(a0 * u),  al1);
                    al2 = fmaf(vv.z, -(a3 * w2), al2);
                    al3 = fmaf(vv.w, -(a2 * w2), al3);
                }
                {
                    const float4 qv = eqhi[a4];
                    float a0 = fmaf(qv.x, yv.x, 1.f);
                    float a1 = fmaf(qv.y, yv.y, 1.f);
                    float a2 = fmaf(qv.z, yv.z, 1.f);
                    float a3 = fmaf(qv.w, yv.w, 1.f);
                    float p01 = a0 * a1, p23 = a2 * a3;
                    float R = __builtin_amdgcn_rcpf(p01 * p23);
                    float t1 = p23 * R, t2 = p01 * R;
                    float u = t1 + t1, w2 = t2 + t2;
                    ah0 = fmaf(vv.x, -(a1 * u),  ah0);
                    ah1 = fmaf(vv.y, -(a0 * u),  ah1);
                    ah2 = fmaf(vv.z, -(a3 * w2), ah2);
                    ah3 = fmaf(vv.w, -(a2 * w2), ah3);
                }
            }
            sc_lo[i] = (al0 + al1) + (al2 + al3);  // garbage t masked below
            sc_hi[i] = (ah0 + ah1) + (ah2 + ah3);
        }
    }

    // ---- softmax (2 q per wave) ----
    #pragma unroll
    for (int j = 0; j < 7; ++j) {
        const int t = j * 64 + lane;
        if (t >= n) { sc_lo[j] = NEG_INF; sc_hi[j] = NEG_INF; }
    }
    float mlo = sc_lo[0], mhi = sc_hi[0];
    #pragma unroll
    for (int j = 1; j < 7; ++j) { mlo = fmaxf(mlo, sc_lo[j]); mhi = fmaxf(mhi, sc_hi[j]); }
    #pragma unroll
    for (int off = 32; off >= 1; off >>= 1) {
        mlo = fmaxf(mlo, __shfl_xor(mlo, off, 64));
        mhi = fmaxf(mhi, __shfl_xor(mhi, off, 64));
    }
    float llo = 0.f, lhi = 0.f;
    #pragma unroll
    for (int j = 0; j < 7; ++j) {
        sc_lo[j] = __builtin_amdgcn_exp2f((sc_lo[j] - mlo) * LOG2E);  // 0 if -inf
        sc_hi[j] = __builtin_amdgcn_exp2f((sc_hi[j] - mhi) * LOG2E);
        llo += sc_lo[j]; lhi += sc_hi[j];
    }
    #pragma unroll
    for (int off = 32; off >= 1; off >>= 1) {
        llo += __shfl_xor(llo, off, 64);
        lhi += __shfl_xor(lhi, off, 64);
    }
    const float invlo = 1.0f / llo, invhi = 1.0f / lhi;
    #pragma unroll
    for (int j = 0; j < 7; ++j) {
        const int t = j * 64 + lane;
        if (t < TYn) {
            s_p[wave][t]     = sc_lo[j] * invlo;   // 2-way bank alias: free
            s_p[wave + 4][t] = sc_hi[j] * invhi;
        }
    }
    __syncthreads();  // s_p visible to all waves

    // ---- apply: y direct from global (L2); p from LDS float4 ----
    const int q   = lane >> 3;                  // 0..7
    const int d4a = (wave << 3) | (lane & 7);   // 0..31
    const int d4b = d4a + 32;                   // 32..63
    const float4* prow4 = reinterpret_cast<const float4*>(&s_p[q][0]);
    float4 acca = {0.f,0.f,0.f,0.f}, accb = {0.f,0.f,0.f,0.f};
    const int n4q = (n + 3) >> 2;               // t-quads, block-uniform
    for (int tq = 0; tq < n4q; ++tq) {
        const float4 pv = prow4[tq];            // conflict-free 8-way pattern
        const float4* yr = yb4 + (size_t)(tq * 4) * 64;
        const float4 A0 = yr[d4a],        B0 = yr[d4b];          // 128B lines
        const float4 A1 = yr[64  + d4a],  B1 = yr[64  + d4b];
        const float4 A2 = yr[128 + d4a],  B2 = yr[128 + d4b];
        const float4 A3 = yr[192 + d4a],  B3 = yr[192 + d4b];
        acca.x = fmaf(pv.x, A0.x, acca.x); acca.y = fmaf(pv.x, A0.y, acca.y);
        acca.z = fmaf(pv.x, A0.z, acca.z); acca.w = fmaf(pv.x, A0.w, acca.w);
        accb.x = fmaf(pv.x, B0.x, accb.x); accb.y = fmaf(pv.x, B0.y, accb.y);
        accb.z = fmaf(pv.x, B0.z, accb.z); accb.w = fmaf(pv.x, B0.w, accb.w);
        acca.x = fmaf(pv.y, A1.x, acca.x); acca.y = fmaf(pv.y, A1.y, acca.y);
        acca.z = fmaf(pv.y, A1.z, acca.z); acca.w = fmaf(pv.y, A1.w, acca.w);
        accb.x = fmaf(pv.y, B1.x, accb.x); accb.y = fmaf(pv.y, B1.y, accb.y);
        accb.z = fmaf(pv.y, B1.z, accb.z); accb.w = fmaf(pv.y, B1.w, accb.w);
        acca.x = fmaf(pv.z, A2.x, acca.x); acca.y = fmaf(pv.z, A2.y, acca.y);
        acca.z = fmaf(pv.z, A2.z, acca.z); acca.w = fmaf(pv.z, A2.w, acca.w);
        accb.x = fmaf(pv.z, B2.x, accb.x); accb.y = fmaf(pv.z, B2.y, accb.y);
        accb.z = fmaf(pv.z, B2.z, accb.z); accb.w = fmaf(pv.z, B2.w, accb.w);
        acca.x = fmaf(pv.w, A3.x, acca.x); acca.y = fmaf(pv.w, A3.y, acca.y);
        acca.z = fmaf(pv.w, A3.z, acca.z); acca.w = fmaf(pv.w, A3.w, acca.w);
        accb.x = fmaf(pv.w, B3.x, accb.x); accb.y = fmaf(pv.w, B3.y, accb.y);
        accb.z = fmaf(pv.w, B3.z, accb.z); accb.w = fmaf(pv.w, B3.w, accb.w);
    }
    float4* o4 = reinterpret_cast<float4*>(out) + (size_t)(b * TQn + q0 + q) * 64;
    o4[d4a] = acca;
    o4[d4b] = accb;
}

extern "C" void kernel_launch(void* const* d_in, const int* in_sizes, int n_in,
                              void* d_out, int out_size, void* d_ws, size_t ws_size,
                              hipStream_t stream) {
    const float* query = (const float*)d_in[0];
    const float* y     = (const float*)d_in[1];
    const float* Wq_w  = (const float*)d_in[2];
    const float* Wq_b  = (const float*)d_in[3];
    const float* Wy_w  = (const float*)d_in[4];
    const float* Wy_b  = (const float*)d_in[5];
    const float* v_w   = (const float*)d_in[6];
    // d_in[7] = v_b: softmax-invariant, dropped.
    const int* nw      = (const int*)d_in[8];
    float* out = (float*)d_out;

    float4* WTq = (float4*)d_ws;                   // 131 KB
    float4* WTy = WTq + 64 * 128;                  // 131 KB
    float*  Eq  = (float*)(WTy + 64 * 128);        // [3200][128] = 1.64 MB
    float*  Ey  = Eq + (size_t)8 * TQn * AD;       // 1.64 MB

    transpose_kernel<<<128, 128, 0, stream>>>(Wq_w, Wy_w, WTq, WTy);
    proj_kernel<<<400, 256, 0, stream>>>(query, y, WTq, Wq_b, WTy, Wy_b, Eq, Ey);
    fused_kernel<<<8 * QBLOCKS, 256, 0, stream>>>(y, Eq, Ey, v_w, nw, out);
}

// Round 11
// 106.173 us; speedup vs baseline: 1.0316x; 1.0316x over previous
//
#include <hip/hip_runtime.h>

// Bahdanau attention. query [8][400][256], y [8][400][256], Wq_w [128][256],
// Wq_b [128], Wy_w [128][256], Wy_b [128], v_w [1][128], v_b (dropped:
// softmax shift-invariant), n_wins_y [8] i32. out [8][400][256] f32.
//
// score = sum_a v_a*tanh(qp+yp) ~ const + sum_a (-2 v_a)/(Eq_a*Ey_a + 1),
// Eq = e^{2 qp}, Ey = e^{2 yp} precomputed (1 fma/elem + 1 rcp/4).
//
// Lesson stack:
//  R4: no runtime-indexed register arrays (scratch spill, 280MB).
//  R7: no lane-scattered global reads (W transposed in K0).
//  R9/R10: LDS pipe was the score bottleneck, BUT moving broadcasts to global
//    only works if addresses are WORKGROUP-uniform (kernel args/blockIdx/loop
//    counters). threadIdx-derived (tid>>6) "wave-uniform" is divergent to LLVM
//    -> vector loads -> R10 regression. R11: q is a UNIFORM LOOP; Ey stored
//    TRANSPOSED in global so lane=t reads are coalesced; score has ZERO LDS.

#define LOG2E 1.4426950408889634f
#define TANH_SCALE 2.8853900817779268f  // 2*log2(e)

constexpr int TQn = 400, TYn = 400, AD = 128, DD = 256;
constexpr int EYLD = 8 * TYn;       // EyT4 row length in float4 (3200 t-cols)
constexpr int PROW = 404;           // s_p row stride floats (404%32=20 -> 8q disjoint banks)

// ---------------- K0: WT4[k4][a] = W[a][4k4..4k4+3]; vneg = -2v ------------
__global__ __launch_bounds__(128) void transpose_kernel(
    const float* __restrict__ Wq, const float* __restrict__ Wy,
    const float* __restrict__ vw,
    float4* __restrict__ WTq, float4* __restrict__ WTy,
    float* __restrict__ vneg)
{
    const int k4 = blockIdx.x & 63;
    const bool isq = blockIdx.x < 64;
    const float4* src = reinterpret_cast<const float4*>(isq ? Wq : Wy);
    float4* dst = isq ? WTq : WTy;
    const int a = threadIdx.x;                 // 0..127
    dst[k4 * 128 + a] = src[a * 64 + k4];
    if (blockIdx.x == 0) vneg[a] = -2.f * vw[a];
}

// ---------------- K1: Eq = exp(2(Wq q + b)) [row][a]; EyT transposed -------
// 128 thr = a only; input-row addresses are workgroup-uniform -> s_load.
__global__ __launch_bounds__(128) void proj_kernel(
    const float* __restrict__ qin, const float* __restrict__ yin,
    const float4* __restrict__ WTq, const float* __restrict__ bq,
    const float4* __restrict__ WTy, const float* __restrict__ by,
    float* __restrict__ Eq, float* __restrict__ EyT)
{
    const int blk = blockIdx.x;               // [0,400) q, [400,800) y
    const bool is_q = blk < 400;
    const int row0 = (is_q ? blk : blk - 400) * 8;   // global row (incl batch)
    const float4* in4 = reinterpret_cast<const float4*>(
        (is_q ? qin : yin) + (size_t)row0 * DD);     // uniform base
    const float4* wt  = is_q ? WTq : WTy;            // [64 k4][128 a]
    const float* bias = is_q ? bq : by;

    const int a = threadIdx.x;                // 0..127
    float acc[8] = {0.f,0.f,0.f,0.f,0.f,0.f,0.f,0.f};
    for (int c = 0; c < 8; ++c) {             // k4 chunk c*8..c*8+7
        float4 wreg[8];
        #pragma unroll
        for (int j = 0; j < 8; ++j)
            wreg[j] = wt[(c * 8 + j) * 128 + a];     // lane-coalesced VMEM
        #pragma unroll
        for (int r = 0; r < 8; ++r) {
            #pragma unroll
            for (int j = 0; j < 8; ++j) {
                float4 v = in4[r * 64 + c * 8 + j];  // UNIFORM -> s_load
                acc[r] = fmaf(wreg[j].x, v.x, acc[r]);
                acc[r] = fmaf(wreg[j].y, v.y, acc[r]);
                acc[r] = fmaf(wreg[j].z, v.z, acc[r]);
                acc[r] = fmaf(wreg[j].w, v.w, acc[r]);
            }
        }
    }
    const float bb = bias[a];
    #pragma unroll
    for (int r = 0; r < 8; ++r) {
        const float e = __builtin_amdgcn_exp2f((acc[r] + bb) * TANH_SCALE);
        if (is_q) Eq[(size_t)(row0 + r) * AD + a] = e;
        else      EyT[(size_t)(a >> 2) * (EYLD * 4) + (size_t)(row0 + r) * 4 + (a & 3)] = e;
    }
}

// ---------------- K2: raw scores; zero LDS, zero barriers ------------------
// block = (b, qgroup4, tile-pair); wave = tile in pair; q is a UNIFORM loop.
__global__ __launch_bounds__(128) void score_kernel(
    const float* __restrict__ Eq,    // [B*TQ][AD]
    const float4* __restrict__ EyT4, // [32 a4][3200 col]
    const float* __restrict__ vneg,  // [AD] = -2v
    const int*  __restrict__ nwins,  // [B]
    float* __restrict__ s)           // [B][TQ][TY]
{
    const int bid  = blockIdx.x;              // 8 * 100 * 4
    const int b    = bid / 400;
    const int rem  = bid % 400;
    const int qg   = rem / 4;
    const int pair = rem % 4;
    const int n = nwins[b];
    const int ntile = (n + 63) >> 6;          // 4..7
    if (pair * 2 >= ntile) return;            // block-uniform early exit
    const int tile = pair * 2 + (threadIdx.x >> 6);  // wave's tile
    const int lane = threadIdx.x & 63;
    const int q0 = qg * 4;

    const float4* eq4 = reinterpret_cast<const float4*>(Eq)
                      + (size_t)(b * TQn + q0) * 32;   // uniform base
    const float4* vn4 = reinterpret_cast<const float4*>(vneg);

    if (tile < ntile) {
        const int t = tile * 64 + lane;
        const int col = b * TYn + min(t, TYn - 1);
        float ac0 = 0.f, ac1 = 0.f, ac2 = 0.f, ac3 = 0.f;
        #pragma unroll 8
        for (int a4 = 0; a4 < 32; ++a4) {
            const float4 ey = EyT4[(size_t)a4 * EYLD + col];  // coalesced 1KB
            const float4 vv = vn4[a4];                        // uniform s_load
            #define SCORE_Q(ACC, QQ)                                        \
            {                                                               \
                const float4 qv = eq4[(QQ) * 32 + a4];  /* uniform s_load */\
                float a0 = fmaf(qv.x, ey.x, 1.f);                           \
                float a1 = fmaf(qv.y, ey.y, 1.f);                           \
                float a2 = fmaf(qv.z, ey.z, 1.f);                           \
                float a3 = fmaf(qv.w, ey.w, 1.f);                           \
                float p01 = a0 * a1, p23 = a2 * a3;                         \
                float R = __builtin_amdgcn_rcpf(p01 * p23);                 \
                float u = p23 * R, w = p01 * R;                             \
                ACC = fmaf(vv.x, a1 * u, ACC);                              \
                ACC = fmaf(vv.y, a0 * u, ACC);                              \
                ACC = fmaf(vv.z, a3 * w, ACC);                              \
                ACC = fmaf(vv.w, a2 * w, ACC);                              \
            }
            SCORE_Q(ac0, 0) SCORE_Q(ac1, 1) SCORE_Q(ac2, 2) SCORE_Q(ac3, 3)
            #undef SCORE_Q
        }
        if (t < TYn) {
            float* srow = s + (size_t)(b * TQn + q0) * TYn + t;
            srow[0]           = ac0;
            srow[TYn]         = ac1;
            srow[2 * TYn]     = ac2;
            srow[3 * TYn]     = ac3;
        }
    }
}

// ---------------- K3: softmax + att@y; QT=8, (q,d4)-lane apply -------------
__global__ __launch_bounds__(512, 2) void apply_kernel(
    const float* __restrict__ y,    // [B][TY][DD]
    const float* __restrict__ s,    // [B][TQ][TY]
    const int*  __restrict__ nwins, // [B]
    float* __restrict__ out)        // [B][TQ][DD]
{
    const int bid = blockIdx.x;               // 8 * 50
    const int b   = bid / 50;
    const int q0  = (bid % 50) * 8;
    const int tid = threadIdx.x, wave = tid >> 6, lane = tid & 63;
    const int n = nwins[b];
    const float NEG_INF = -__builtin_inff();

    __shared__ __align__(16) float s_p[8][PROW];   // 12.9 KB

    // ---- softmax for q = q0 + wave (8 waves, proven R8/R9 code) ----
    const float* srow = s + (size_t)(b * TQn + q0 + wave) * TYn;
    float sc0, sc1, sc2, sc3, sc4, sc5, sc6;
    {
        int t;
        t = 0 * 64 + lane; sc0 = (t < n) ? srow[t] : NEG_INF;
        t = 1 * 64 + lane; sc1 = (t < n) ? srow[t] : NEG_INF;
        t = 2 * 64 + lane; sc2 = (t < n) ? srow[t] : NEG_INF;
        t = 3 * 64 + lane; sc3 = (t < n) ? srow[t] : NEG_INF;
        t = 4 * 64 + lane; sc4 = (t < n) ? srow[t] : NEG_INF;
        t = 5 * 64 + lane; sc5 = (t < n) ? srow[t] : NEG_INF;
        t = 6 * 64 + lane; sc6 = (t < n) ? srow[t] : NEG_INF;
    }
    float m = fmaxf(fmaxf(fmaxf(sc0, sc1), fmaxf(sc2, sc3)),
                    fmaxf(fmaxf(sc4, sc5), sc6));
    #pragma unroll
    for (int off = 32; off >= 1; off >>= 1) m = fmaxf(m, __shfl_xor(m, off, 64));
    sc0 = __builtin_amdgcn_exp2f((sc0 - m) * LOG2E);
    sc1 = __builtin_amdgcn_exp2f((sc1 - m) * LOG2E);
    sc2 = __builtin_amdgcn_exp2f((sc2 - m) * LOG2E);
    sc3 = __builtin_amdgcn_exp2f((sc3 - m) * LOG2E);
    sc4 = __builtin_amdgcn_exp2f((sc4 - m) * LOG2E);
    sc5 = __builtin_amdgcn_exp2f((sc5 - m) * LOG2E);
    sc6 = __builtin_amdgcn_exp2f((sc6 - m) * LOG2E);
    float l = ((sc0 + sc1) + (sc2 + sc3)) + ((sc4 + sc5) + sc6);
    #pragma unroll
    for (int off = 32; off >= 1; off >>= 1) l += __shfl_xor(l, off, 64);
    const float inv = 1.0f / l;
    s_p[wave][0 * 64 + lane] = sc0 * inv;     // 0 beyond n (exp2(-inf)=0)
    s_p[wave][1 * 64 + lane] = sc1 * inv;
    s_p[wave][2 * 64 + lane] = sc2 * inv;
    s_p[wave][3 * 64 + lane] = sc3 * inv;
    s_p[wave][4 * 64 + lane] = sc4 * inv;
    s_p[wave][5 * 64 + lane] = sc5 * inv;
    {
        const int t = 6 * 64 + lane;          // up to 447: keep within [PROW)
        if (t < TYn) s_p[wave][t] = sc6 * inv;
    }
    __syncthreads();

    // ---- apply: thread = (q = lane>>3, d4 = wave*8 + lane&7) ----
    const int q  = lane >> 3;                  // 0..7
    const int d4 = (wave << 3) | (lane & 7);   // 0..63
    const float4* prow4 = reinterpret_cast<const float4*>(&s_p[q][0]);
    const float4* yb4 = reinterpret_cast<const float4*>(y) + (size_t)(b * TYn) * 64;
    float4 acc = {0.f, 0.f, 0.f, 0.f};
    const int n4q = (n + 3) >> 2;              // t-quads; p zero-padded to 400
    for (int tq = 0; tq < n4q; ++tq) {
        const float4 pv = prow4[tq];           // 8 q -> 8 disjoint bank-quads
        const float4* yr = yb4 + (size_t)(tq * 4) * 64;
        const float4 y0 = yr[d4];              // 128B coalesced, 8-way bcast
        const float4 y1 = yr[64 + d4];
        const float4 y2 = yr[128 + d4];
        const float4 y3 = yr[192 + d4];
        acc.x = fmaf(pv.x, y0.x, acc.x); acc.y = fmaf(pv.x, y0.y, acc.y);
        acc.z = fmaf(pv.x, y0.z, acc.z); acc.w = fmaf(pv.x, y0.w, acc.w);
        acc.x = fmaf(pv.y, y1.x, acc.x); acc.y = fmaf(pv.y, y1.y, acc.y);
        acc.z = fmaf(pv.y, y1.z, acc.z); acc.w = fmaf(pv.y, y1.w, acc.w);
        acc.x = fmaf(pv.z, y2.x, acc.x); acc.y = fmaf(pv.z, y2.y, acc.y);
        acc.z = fmaf(pv.z, y2.z, acc.z); acc.w = fmaf(pv.z, y2.w, acc.w);
        acc.x = fmaf(pv.w, y3.x, acc.x); acc.y = fmaf(pv.w, y3.y, acc.y);
        acc.z = fmaf(pv.w, y3.z, acc.z); acc.w = fmaf(pv.w, y3.w, acc.w);
    }
    reinterpret_cast<float4*>(out)[(size_t)(b * TQn + q0 + q) * 64 + d4] = acc;
}

extern "C" void kernel_launch(void* const* d_in, const int* in_sizes, int n_in,
                              void* d_out, int out_size, void* d_ws, size_t ws_size,
                              hipStream_t stream) {
    const float* query = (const float*)d_in[0];
    const float* y     = (const float*)d_in[1];
    const float* Wq_w  = (const float*)d_in[2];
    const float* Wq_b  = (const float*)d_in[3];
    const float* Wy_w  = (const float*)d_in[4];
    const float* Wy_b  = (const float*)d_in[5];
    const float* v_w   = (const float*)d_in[6];
    // d_in[7] = v_b: softmax-invariant, dropped.
    const int* nw      = (const int*)d_in[8];
    float* out = (float*)d_out;

    float4* WTq  = (float4*)d_ws;                    // 131 KB
    float4* WTy  = WTq + 64 * 128;                   // 131 KB
    float*  vneg = (float*)(WTy + 64 * 128);         // 512 B (pad to 256 f4)
    float*  Eq   = vneg + 1024;                      // [3200][128] = 1.64 MB
    float*  EyT  = Eq + (size_t)8 * TQn * AD;        // [32][3200] f4 = 1.64 MB
    float*  s    = EyT + (size_t)32 * EYLD * 4;      // [8][400][400] = 5.12 MB

    transpose_kernel<<<128, 128, 0, stream>>>(Wq_w, Wy_w, v_w, WTq, WTy, vneg);
    proj_kernel<<<800, 128, 0, stream>>>(query, y, WTq, Wq_b, WTy, Wy_b, Eq, EyT);
    score_kernel<<<8 * 100 * 4, 128, 0, stream>>>(
        Eq, (const float4*)EyT, vneg, nw, s);
    apply_kernel<<<8 * 50, 512, 0, stream>>>(y, s, nw, out);
}